// Round 12
// baseline (224.808 us; speedup 1.0000x reference)
//
#include <hip/hip_runtime.h>
#include <stdint.h>

#define N_NODES 100000
#define FEAT 64
#define SCAN_B 1024
#define BKT 256                                  // dst nodes per bucket
#define NBINS ((N_NODES + BKT - 1) / BKT)        // 391
#define NTILES 256
#define NSLICE 8                                 // 8 feature slices x 16B
#define SRC_MASK 0x00FFFFFFu

typedef __attribute__((ext_vector_type(8))) short bf16x8;
typedef __attribute__((ext_vector_type(4))) float f32x4;

__device__ __forceinline__ unsigned short f2bf(float f) {
    unsigned int u = __float_as_uint(f);
    u += 0x7fffu + ((u >> 16) & 1u);  // RNE
    return (unsigned short)(u >> 16);
}

// ---- one-time fp32 -> bf16 conversion into SLICED layout ----
// xb_cs[c*N + n] (uint4) = features [c*8, c*8+8) of node n.
__global__ __launch_bounds__(256) void cvt_bf16_sliced_kernel(
    const float* __restrict__ in, uint4* __restrict__ out_cs, int n8) {
    int i = blockIdx.x * blockDim.x + threadIdx.x;
    if (i >= n8) return;
    int node = i >> 3, c = i & 7;
    const float4* p = (const float4*)(in + (size_t)node * FEAT + c * 8);
    float4 a = p[0];
    float4 b = p[1];
    uint4 r;
    r.x = (unsigned int)f2bf(a.x) | ((unsigned int)f2bf(a.y) << 16);
    r.y = (unsigned int)f2bf(a.z) | ((unsigned int)f2bf(a.w) << 16);
    r.z = (unsigned int)f2bf(b.x) | ((unsigned int)f2bf(b.y) << 16);
    r.w = (unsigned int)f2bf(b.z) | ((unsigned int)f2bf(b.w) << 16);
    out_cs[(size_t)c * N_NODES + node] = r;
}

// ---- bucket partition build (proven cheap R8-R11) ----

__global__ __launch_bounds__(256) void tile_hist_kernel(
    const int* __restrict__ dst, int* __restrict__ H, int nE, int tileEdges) {
    __shared__ int hist[NBINS];
    const int tile = blockIdx.x;
    const int tid = threadIdx.x;
    for (int i = tid; i < NBINS; i += 256) hist[i] = 0;
    __syncthreads();
    int e0 = tile * tileEdges;
    int e1 = min(e0 + tileEdges, nE);
    for (int e = e0 + tid; e < e1; e += 256) atomicAdd(&hist[dst[e] >> 8], 1);
    __syncthreads();
    for (int i = tid; i < NBINS; i += 256) H[i * NTILES + tile] = hist[i];
}

__global__ __launch_bounds__(SCAN_B) void scan1_kernel(
    const int* __restrict__ deg, int* __restrict__ P,
    int* __restrict__ bsum, int n) {
    __shared__ int tmp[SCAN_B];
    int t = threadIdx.x;
    int gid = blockIdx.x * SCAN_B + t;
    int v = (gid < n) ? deg[gid] : 0;
    tmp[t] = v;
    __syncthreads();
    for (int off = 1; off < SCAN_B; off <<= 1) {
        int a = (t >= off) ? tmp[t - off] : 0;
        __syncthreads();
        tmp[t] += a;
        __syncthreads();
    }
    if (gid < n) P[gid] = tmp[t] - v;  // exclusive
    if (t == SCAN_B - 1) bsum[blockIdx.x] = tmp[t];
}

__global__ __launch_bounds__(128) void scan2_kernel(int* __restrict__ bsum, int nb) {
    __shared__ int tmp[128];
    int t = threadIdx.x;
    int v = (t < nb) ? bsum[t] : 0;
    tmp[t] = v;
    __syncthreads();
    for (int off = 1; off < 128; off <<= 1) {
        int a = (t >= off) ? tmp[t - off] : 0;
        __syncthreads();
        tmp[t] += a;
        __syncthreads();
    }
    if (t < nb) bsum[t] = tmp[t] - v;  // exclusive
}

__global__ __launch_bounds__(256) void scan3_kernel(
    int* __restrict__ P, const int* __restrict__ bsum, int n, int total) {
    int gid = blockIdx.x * blockDim.x + threadIdx.x;
    if (gid < n) P[gid] += bsum[gid >> 10];
    if (gid == 0) P[n] = total;
}

__global__ __launch_bounds__(256) void scatter_bucket_kernel(
    const int* __restrict__ src, const int* __restrict__ dst,
    const int* __restrict__ P, unsigned int* __restrict__ packed,
    int nE, int tileEdges) {
    __shared__ int cur[NBINS];
    const int tile = blockIdx.x;
    const int tid = threadIdx.x;
    for (int i = tid; i < NBINS; i += 256) cur[i] = P[i * NTILES + tile];
    __syncthreads();
    int e0 = tile * tileEdges;
    int e1 = min(e0 + tileEdges, nE);
    for (int e = e0 + tid; e < e1; e += 256) {
        int d = dst[e];
        int pos = atomicAdd(&cur[d >> 8], 1);
        packed[pos] = ((unsigned int)(d & (BKT - 1)) << 24) | (unsigned int)src[e];
    }
}

// Local counting sort within each bucket -> exact dst-sorted ssrc + rowptr.
__global__ __launch_bounds__(256) void bucket_sort_kernel(
    const unsigned int* __restrict__ packed,
    const int* __restrict__ P,
    int* __restrict__ rowptr,
    int* __restrict__ ssrc,
    int nE) {
    __shared__ int hist[BKT];
    __shared__ int cur[BKT];
    const int b = blockIdx.x;
    const int tid = threadIdx.x;

    hist[tid] = 0;
    __syncthreads();
    const int start = P[b * NTILES];
    const int end = (b + 1 < NBINS) ? P[(b + 1) * NTILES] : nE;
    for (int j = start + tid; j < end; j += 256)
        atomicAdd(&hist[packed[j] >> 24], 1);
    __syncthreads();

    int v = hist[tid];
    for (int off = 1; off < 256; off <<= 1) {
        int a = (tid >= off) ? hist[tid - off] : 0;
        __syncthreads();
        hist[tid] += a;
        __syncthreads();
    }
    int excl = hist[tid] - v;

    int node = b * BKT + tid;
    if (node <= N_NODES) rowptr[node] = start + excl;
    cur[tid] = start + excl;
    __syncthreads();

    for (int j = start + tid; j < end; j += 256) {
        unsigned int p = packed[j];
        int pos = atomicAdd(&cur[p >> 24], 1);
        ssrc[pos] = (int)(p & SRC_MASK);
    }
}

// XCD-sliced mean aggregation: block (bin = blockIdx/8, c = blockIdx%8).
// Round-robin blockIdx->XCD puts all slice-c blocks on XCD c, so XCD c's
// gathers touch only feat_cs[c*N .. (c+1)*N) = 1.6MB < 4MB L2 -> compulsory
// fetch once, then L2 hits. One thread per dst node, serial over its edges,
// 4x unroll for MLP.
__global__ __launch_bounds__(256) void agg_sliced_kernel(
    const uint4* __restrict__ feat_cs,   // [8][N] sliced bf16
    const int* __restrict__ rowptr,
    const int* __restrict__ ssrc,
    uint4* __restrict__ mean_cs,         // [8][N] sliced bf16
    int nNodes) {
    const int c = blockIdx.x & 7;
    const int bin = blockIdx.x >> 3;
    const int node = bin * BKT + threadIdx.x;
    if (node >= nNodes) return;
    const uint4* fs = feat_cs + (size_t)c * N_NODES;

    int beg = rowptr[node];
    int end = rowptr[node + 1];
    float acc0 = 0.f, acc1 = 0.f, acc2 = 0.f, acc3 = 0.f;
    float acc4 = 0.f, acc5 = 0.f, acc6 = 0.f, acc7 = 0.f;

#define ADDROW(a)                                         \
    acc0 += __uint_as_float((a).x << 16);                 \
    acc1 += __uint_as_float((a).x & 0xffff0000u);         \
    acc2 += __uint_as_float((a).y << 16);                 \
    acc3 += __uint_as_float((a).y & 0xffff0000u);         \
    acc4 += __uint_as_float((a).z << 16);                 \
    acc5 += __uint_as_float((a).z & 0xffff0000u);         \
    acc6 += __uint_as_float((a).w << 16);                 \
    acc7 += __uint_as_float((a).w & 0xffff0000u);

    int j = beg;
    for (; j + 4 <= end; j += 4) {
        int s0 = ssrc[j + 0];
        int s1 = ssrc[j + 1];
        int s2 = ssrc[j + 2];
        int s3 = ssrc[j + 3];
        uint4 a0 = fs[s0];
        uint4 a1 = fs[s1];
        uint4 a2 = fs[s2];
        uint4 a3 = fs[s3];
        ADDROW(a0) ADDROW(a1) ADDROW(a2) ADDROW(a3)
    }
    for (; j < end; ++j) {
        uint4 a = fs[ssrc[j]];
        ADDROW(a)
    }
#undef ADDROW

    int deg = end - beg;
    float inv = 1.0f / (float)(deg > 0 ? deg : 1);
    uint4 r;
    r.x = (unsigned int)f2bf(acc0 * inv) | ((unsigned int)f2bf(acc1 * inv) << 16);
    r.y = (unsigned int)f2bf(acc2 * inv) | ((unsigned int)f2bf(acc3 * inv) << 16);
    r.z = (unsigned int)f2bf(acc4 * inv) | ((unsigned int)f2bf(acc5 * inv) << 16);
    r.w = (unsigned int)f2bf(acc6 * inv) | ((unsigned int)f2bf(acc7 * inv) << 16);
    mean_cs[(size_t)c * N_NODES + node] = r;  // coalesced per block
}

// ---- MFMA linear: out = relu([mean|x] @ [Wl|Wr]^T + b), sliced inputs ----

__device__ __forceinline__ bf16x8 pack8(const float* __restrict__ p) {
    float4 a = *(const float4*)p;
    float4 b = *(const float4*)(p + 4);
    bf16x8 r;
    r[0] = (short)f2bf(a.x); r[1] = (short)f2bf(a.y);
    r[2] = (short)f2bf(a.z); r[3] = (short)f2bf(a.w);
    r[4] = (short)f2bf(b.x); r[5] = (short)f2bf(b.y);
    r[6] = (short)f2bf(b.z); r[7] = (short)f2bf(b.w);
    return r;
}

// A-fragment K-chunk kk, lane group kg reads feature slice s=(kk&1)*4+kg of
// mean (kk<2) or x (kk>=2): a single uint4 at [s*N + arow] (coalesced).
// OUT_BF16 writes sliced bf16 (for layer-2 reuse); else fp32 row-major.
template <bool OUT_BF16>
__global__ __launch_bounds__(256) void mfma_linear_kernel(
    const uint4* __restrict__ mean_cs,  // [8][N] sliced bf16
    const uint4* __restrict__ x_cs,     // [8][N] sliced bf16
    const float* __restrict__ Wl,
    const float* __restrict__ bias,
    const float* __restrict__ Wr,
    void* __restrict__ outp,
    int nGroups) {
    const int lane = (int)(threadIdx.x & 63);
    const int col = lane & 15;
    const int kg = lane >> 4;

    bf16x8 bfr[4][4];
#pragma unroll
    for (int t = 0; t < 4; ++t) {
        const int n = t * 16 + col;
#pragma unroll
        for (int kk = 0; kk < 4; ++kk) {
            const float* w = (kk < 2 ? Wl : Wr) + n * 64 + (kk & 1) * 32 + kg * 8;
            bfr[t][kk] = pack8(w);
        }
    }
    float bv[4];
#pragma unroll
    for (int t = 0; t < 4; ++t) bv[t] = bias[t * 16 + col];

    const int wave = (int)((blockIdx.x * blockDim.x + threadIdx.x) >> 6);
    const int nWaves = (int)((gridDim.x * blockDim.x) >> 6);

    for (int g = wave; g < nGroups; g += nWaves) {
        const int arow = g * 16 + col;

        f32x4 acc[4];
#pragma unroll
        for (int t = 0; t < 4; ++t) acc[t] = (f32x4){0.f, 0.f, 0.f, 0.f};

#pragma unroll
        for (int kk = 0; kk < 4; ++kk) {
            const int s = (kk & 1) * 4 + kg;
            const uint4* base = (kk < 2) ? mean_cs : x_cs;
            uint4 av = base[(size_t)s * N_NODES + arow];
            bf16x8 a = *(const bf16x8*)&av;
#pragma unroll
            for (int t = 0; t < 4; ++t)
                acc[t] = __builtin_amdgcn_mfma_f32_16x16x32_bf16(a, bfr[t][kk], acc[t], 0, 0, 0);
        }

#pragma unroll
        for (int t = 0; t < 4; ++t) {
#pragma unroll
            for (int r = 0; r < 4; ++r) {
                int node = g * 16 + kg * 4 + r;
                float v = fmaxf(acc[t][r] + bv[t], 0.0f);
                if (OUT_BF16) {
                    int f = t * 16 + col;
                    int slice = f >> 3;
                    ((unsigned short*)outp)[((size_t)slice * N_NODES + node) * 8 + (f & 7)] = f2bf(v);
                } else {
                    ((float*)outp)[(size_t)node * FEAT + t * 16 + col] = v;
                }
            }
        }
    }
}

extern "C" void kernel_launch(void* const* d_in, const int* in_sizes, int n_in,
                              void* d_out, int out_size, void* d_ws, size_t ws_size,
                              hipStream_t stream) {
    const float* x   = (const float*)d_in[0];
    const int* ei    = (const int*)d_in[1];
    const float* Wl1 = (const float*)d_in[2];
    const float* b1  = (const float*)d_in[3];
    const float* Wr1 = (const float*)d_in[4];
    const float* Wl2 = (const float*)d_in[5];
    const float* b2  = (const float*)d_in[6];
    const float* Wr2 = (const float*)d_in[7];

    const int E = in_sizes[1] / 2;  // 1,600,000
    const int* src = ei;
    const int* dst = ei + E;
    const int N = N_NODES;

    const int n2 = NBINS * NTILES;               // 100096
    const int TE = (E + NTILES - 1) / NTILES;    // 6250
    const int NB2 = (n2 + SCAN_B - 1) / SCAN_B;  // 98

    // workspace layout (int-counts %4==0 -> all uint4 buffers 16B-aligned)
    int* H      = (int*)d_ws;                            // n2
    int* P      = H + n2;                                // n2+8
    int* bsum   = P + (n2 + 8);                          // 128
    unsigned int* packed = (unsigned int*)(bsum + 128);  // E
    int* rowptr = (int*)(packed + E);                    // N+8
    int* ssrc   = rowptr + (N + 8);                      // E
    uint4* mean_cs = (uint4*)(ssrc + E);                 // 8*N uint4 (12.8MB)
    uint4* x_cs    = mean_cs + (size_t)NSLICE * N;       // 8*N uint4
    uint4* h_cs    = x_cs + (size_t)NSLICE * N;          // 8*N uint4
    float* out  = (float*)d_out;

    const int NG = N / 16;  // 6250 MFMA node-groups

    // ---- feature conversion + partition/sort (reused by both layers) ----
    cvt_bf16_sliced_kernel<<<(N * 8 + 255) / 256, 256, 0, stream>>>(x, x_cs, N * 8);
    tile_hist_kernel<<<NTILES, 256, 0, stream>>>(dst, H, E, TE);
    scan1_kernel<<<NB2, SCAN_B, 0, stream>>>(H, P, bsum, n2);
    scan2_kernel<<<1, 128, 0, stream>>>(bsum, NB2);
    scan3_kernel<<<(n2 + 256) / 256, 256, 0, stream>>>(P, bsum, n2, E);
    scatter_bucket_kernel<<<NTILES, 256, 0, stream>>>(src, dst, P, packed, E, TE);
    bucket_sort_kernel<<<NBINS, 256, 0, stream>>>(packed, P, rowptr, ssrc, E);

    // ---- layer 1 ----
    agg_sliced_kernel<<<NBINS * NSLICE, 256, 0, stream>>>(x_cs, rowptr, ssrc, mean_cs, N);
    mfma_linear_kernel<true><<<256, 256, 0, stream>>>(mean_cs, x_cs, Wl1, b1, Wr1, h_cs, NG);

    // ---- layer 2 ----
    agg_sliced_kernel<<<NBINS * NSLICE, 256, 0, stream>>>(h_cs, rowptr, ssrc, mean_cs, N);
    mfma_linear_kernel<false><<<256, 256, 0, stream>>>(mean_cs, h_cs, Wl2, b2, Wr2, out, NG);
}

// Round 13
// 182.574 us; speedup vs baseline: 1.2313x; 1.2313x over previous
//
#include <hip/hip_runtime.h>
#include <stdint.h>

#define N_NODES 100000
#define FEAT 64
#define SCAN_B 1024
#define BKT 256                                  // dst nodes per bucket
#define NBINS ((N_NODES + BKT - 1) / BKT)        // 391
#define NTILES 1024                              // edge tiles (4 wg/CU)
#define SRC_MASK 0x00FFFFFFu

typedef __attribute__((ext_vector_type(8))) short bf16x8;
typedef __attribute__((ext_vector_type(4))) float f32x4;

__device__ __forceinline__ unsigned short f2bf(float f) {
    unsigned int u = __float_as_uint(f);
    u += 0x7fffu + ((u >> 16) & 1u);  // RNE
    return (unsigned short)(u >> 16);
}

// ---- one-time fp32 -> bf16 feature conversion ----
__global__ __launch_bounds__(256) void cvt_bf16_kernel(
    const float* __restrict__ in, unsigned short* __restrict__ out, int n8) {
    int i = blockIdx.x * blockDim.x + threadIdx.x;
    if (i >= n8) return;
    float4 a = ((const float4*)in)[i * 2];
    float4 b = ((const float4*)in)[i * 2 + 1];
    uint4 r;
    r.x = (unsigned int)f2bf(a.x) | ((unsigned int)f2bf(a.y) << 16);
    r.y = (unsigned int)f2bf(a.z) | ((unsigned int)f2bf(a.w) << 16);
    r.z = (unsigned int)f2bf(b.x) | ((unsigned int)f2bf(b.y) << 16);
    r.w = (unsigned int)f2bf(b.z) | ((unsigned int)f2bf(b.w) << 16);
    ((uint4*)out)[i] = r;
}

// ---- bucket partition build ----

__global__ __launch_bounds__(256) void tile_hist_kernel(
    const int* __restrict__ dst, int* __restrict__ H, int nE, int tileEdges) {
    __shared__ int hist[NBINS];
    const int tile = blockIdx.x;
    const int tid = threadIdx.x;
    for (int i = tid; i < NBINS; i += 256) hist[i] = 0;
    __syncthreads();
    int e0 = tile * tileEdges;
    int e1 = min(e0 + tileEdges, nE);
    for (int e = e0 + tid; e < e1; e += 256) atomicAdd(&hist[dst[e] >> 8], 1);
    __syncthreads();
    for (int i = tid; i < NBINS; i += 256) H[i * NTILES + tile] = hist[i];
}

__global__ __launch_bounds__(SCAN_B) void scan1_kernel(
    const int* __restrict__ deg, int* __restrict__ P,
    int* __restrict__ bsum, int n) {
    __shared__ int tmp[SCAN_B];
    int t = threadIdx.x;
    int gid = blockIdx.x * SCAN_B + t;
    int v = (gid < n) ? deg[gid] : 0;
    tmp[t] = v;
    __syncthreads();
    for (int off = 1; off < SCAN_B; off <<= 1) {
        int a = (t >= off) ? tmp[t - off] : 0;
        __syncthreads();
        tmp[t] += a;
        __syncthreads();
    }
    if (gid < n) P[gid] = tmp[t] - v;  // exclusive
    if (t == SCAN_B - 1) bsum[blockIdx.x] = tmp[t];
}

// Exclusive scan of <=512 block sums, single block of 512 threads.
__global__ __launch_bounds__(512) void scan2_kernel(int* __restrict__ bsum, int nb) {
    __shared__ int tmp[512];
    int t = threadIdx.x;
    int v = (t < nb) ? bsum[t] : 0;
    tmp[t] = v;
    __syncthreads();
    for (int off = 1; off < 512; off <<= 1) {
        int a = (t >= off) ? tmp[t - off] : 0;
        __syncthreads();
        tmp[t] += a;
        __syncthreads();
    }
    if (t < nb) bsum[t] = tmp[t] - v;  // exclusive
}

__global__ __launch_bounds__(256) void scan3_kernel(
    int* __restrict__ P, const int* __restrict__ bsum, int n, int total) {
    int gid = blockIdx.x * blockDim.x + threadIdx.x;
    if (gid < n) P[gid] += bsum[gid >> 10];
    if (gid == 0) P[n] = total;
}

__global__ __launch_bounds__(256) void scatter_bucket_kernel(
    const int* __restrict__ src, const int* __restrict__ dst,
    const int* __restrict__ P, unsigned int* __restrict__ packed,
    int nE, int tileEdges) {
    __shared__ int cur[NBINS];
    const int tile = blockIdx.x;
    const int tid = threadIdx.x;
    for (int i = tid; i < NBINS; i += 256) cur[i] = P[i * NTILES + tile];
    __syncthreads();
    int e0 = tile * tileEdges;
    int e1 = min(e0 + tileEdges, nE);
    for (int e = e0 + tid; e < e1; e += 256) {
        int d = dst[e];
        int pos = atomicAdd(&cur[d >> 8], 1);
        packed[pos] = ((unsigned int)(d & (BKT - 1)) << 24) | (unsigned int)src[e];
    }
}

// Local counting sort within each bucket -> exact dst-sorted ssrc + rowptr.
__global__ __launch_bounds__(256) void bucket_sort_kernel(
    const unsigned int* __restrict__ packed,
    const int* __restrict__ P,
    int* __restrict__ rowptr,
    int* __restrict__ ssrc,
    int nE) {
    __shared__ int hist[BKT];
    __shared__ int cur[BKT];
    const int b = blockIdx.x;
    const int tid = threadIdx.x;

    hist[tid] = 0;
    __syncthreads();
    const int start = P[b * NTILES];
    const int end = (b + 1 < NBINS) ? P[(b + 1) * NTILES] : nE;
    for (int j = start + tid; j < end; j += 256)
        atomicAdd(&hist[packed[j] >> 24], 1);
    __syncthreads();

    int v = hist[tid];
    for (int off = 1; off < 256; off <<= 1) {
        int a = (tid >= off) ? hist[tid - off] : 0;
        __syncthreads();
        hist[tid] += a;
        __syncthreads();
    }
    int excl = hist[tid] - v;

    int node = b * BKT + tid;
    if (node <= N_NODES) rowptr[node] = start + excl;
    cur[tid] = start + excl;
    __syncthreads();

    for (int j = start + tid; j < end; j += 256) {
        unsigned int p = packed[j];
        int pos = atomicAdd(&cur[p >> 24], 1);
        ssrc[pos] = (int)(p & SRC_MASK);
    }
}

// Mean aggregation over bf16 features: 8 lanes per node (16B each), 8x
// unroll. At the measured random-gather fetch-path plateau (~3.4 TB/s).
__global__ __launch_bounds__(256) void agg_bf16_kernel(
    const unsigned short* __restrict__ featb,   // [N][64] bf16
    const int* __restrict__ rowptr,
    const int* __restrict__ ssrc,
    unsigned short* __restrict__ meanb,         // [N][64] bf16
    int nNodes) {
    int tid = blockIdx.x * blockDim.x + threadIdx.x;
    int node = tid >> 3;
    if (node >= nNodes) return;
    int chunk = tid & 7;  // 8 lanes/node, 16B (8 bf16) each
    const uint4* feat16 = (const uint4*)featb;  // row = 8 x uint4

    int beg = rowptr[node];
    int end = rowptr[node + 1];
    float acc0 = 0.f, acc1 = 0.f, acc2 = 0.f, acc3 = 0.f;
    float acc4 = 0.f, acc5 = 0.f, acc6 = 0.f, acc7 = 0.f;

#define ADDROW(a)                                         \
    acc0 += __uint_as_float((a).x << 16);                 \
    acc1 += __uint_as_float((a).x & 0xffff0000u);         \
    acc2 += __uint_as_float((a).y << 16);                 \
    acc3 += __uint_as_float((a).y & 0xffff0000u);         \
    acc4 += __uint_as_float((a).z << 16);                 \
    acc5 += __uint_as_float((a).z & 0xffff0000u);         \
    acc6 += __uint_as_float((a).w << 16);                 \
    acc7 += __uint_as_float((a).w & 0xffff0000u);

    int j = beg;
    for (; j + 8 <= end; j += 8) {
        int s0 = ssrc[j + 0];
        int s1 = ssrc[j + 1];
        int s2 = ssrc[j + 2];
        int s3 = ssrc[j + 3];
        int s4 = ssrc[j + 4];
        int s5 = ssrc[j + 5];
        int s6 = ssrc[j + 6];
        int s7 = ssrc[j + 7];
        uint4 a0 = feat16[(size_t)s0 * 8 + chunk];
        uint4 a1 = feat16[(size_t)s1 * 8 + chunk];
        uint4 a2 = feat16[(size_t)s2 * 8 + chunk];
        uint4 a3 = feat16[(size_t)s3 * 8 + chunk];
        uint4 a4 = feat16[(size_t)s4 * 8 + chunk];
        uint4 a5 = feat16[(size_t)s5 * 8 + chunk];
        uint4 a6 = feat16[(size_t)s6 * 8 + chunk];
        uint4 a7 = feat16[(size_t)s7 * 8 + chunk];
        ADDROW(a0) ADDROW(a1) ADDROW(a2) ADDROW(a3)
        ADDROW(a4) ADDROW(a5) ADDROW(a6) ADDROW(a7)
    }
    for (; j + 4 <= end; j += 4) {
        int s0 = ssrc[j + 0];
        int s1 = ssrc[j + 1];
        int s2 = ssrc[j + 2];
        int s3 = ssrc[j + 3];
        uint4 a0 = feat16[(size_t)s0 * 8 + chunk];
        uint4 a1 = feat16[(size_t)s1 * 8 + chunk];
        uint4 a2 = feat16[(size_t)s2 * 8 + chunk];
        uint4 a3 = feat16[(size_t)s3 * 8 + chunk];
        ADDROW(a0) ADDROW(a1) ADDROW(a2) ADDROW(a3)
    }
    for (; j < end; ++j) {
        uint4 a = feat16[(size_t)ssrc[j] * 8 + chunk];
        ADDROW(a)
    }
#undef ADDROW

    int deg = end - beg;
    float inv = 1.0f / (float)(deg > 0 ? deg : 1);
    uint4 r;
    r.x = (unsigned int)f2bf(acc0 * inv) | ((unsigned int)f2bf(acc1 * inv) << 16);
    r.y = (unsigned int)f2bf(acc2 * inv) | ((unsigned int)f2bf(acc3 * inv) << 16);
    r.z = (unsigned int)f2bf(acc4 * inv) | ((unsigned int)f2bf(acc5 * inv) << 16);
    r.w = (unsigned int)f2bf(acc6 * inv) | ((unsigned int)f2bf(acc7 * inv) << 16);
    ((uint4*)meanb)[(size_t)node * 8 + chunk] = r;
}

// ---- MFMA linear: out = relu([mean|x] @ [Wl|Wr]^T + b) ----

__device__ __forceinline__ bf16x8 pack8(const float* __restrict__ p) {
    float4 a = *(const float4*)p;
    float4 b = *(const float4*)(p + 4);
    bf16x8 r;
    r[0] = (short)f2bf(a.x); r[1] = (short)f2bf(a.y);
    r[2] = (short)f2bf(a.z); r[3] = (short)f2bf(a.w);
    r[4] = (short)f2bf(b.x); r[5] = (short)f2bf(b.y);
    r[6] = (short)f2bf(b.z); r[7] = (short)f2bf(b.w);
    return r;
}

template <bool OUT_BF16>
__global__ __launch_bounds__(256) void mfma_linear_kernel(
    const unsigned short* __restrict__ meanb,  // [N][64] bf16
    const unsigned short* __restrict__ xb,     // [N][64] bf16
    const float* __restrict__ Wl,
    const float* __restrict__ bias,
    const float* __restrict__ Wr,
    void* __restrict__ outp,
    int nGroups) {
    const int lane = (int)(threadIdx.x & 63);
    const int col = lane & 15;
    const int kg = lane >> 4;

    bf16x8 bfr[4][4];
#pragma unroll
    for (int t = 0; t < 4; ++t) {
        const int n = t * 16 + col;
#pragma unroll
        for (int kk = 0; kk < 4; ++kk) {
            const float* w = (kk < 2 ? Wl : Wr) + n * 64 + (kk & 1) * 32 + kg * 8;
            bfr[t][kk] = pack8(w);
        }
    }
    float bv[4];
#pragma unroll
    for (int t = 0; t < 4; ++t) bv[t] = bias[t * 16 + col];

    const int wave = (int)((blockIdx.x * blockDim.x + threadIdx.x) >> 6);
    const int nWaves = (int)((gridDim.x * blockDim.x) >> 6);

    for (int g = wave; g < nGroups; g += nWaves) {
        const int arow = g * 16 + col;
        const unsigned short* mrow = meanb + (size_t)arow * FEAT + kg * 8;
        const unsigned short* xrow = xb + (size_t)arow * FEAT + kg * 8;

        f32x4 acc[4];
#pragma unroll
        for (int t = 0; t < 4; ++t) acc[t] = (f32x4){0.f, 0.f, 0.f, 0.f};

#pragma unroll
        for (int kk = 0; kk < 4; ++kk) {
            const unsigned short* p =
                (kk < 2) ? (mrow + (kk & 1) * 32) : (xrow + (kk & 1) * 32);
            bf16x8 a = *(const bf16x8*)p;
#pragma unroll
            for (int t = 0; t < 4; ++t)
                acc[t] = __builtin_amdgcn_mfma_f32_16x16x32_bf16(a, bfr[t][kk], acc[t], 0, 0, 0);
        }

#pragma unroll
        for (int t = 0; t < 4; ++t) {
#pragma unroll
            for (int r = 0; r < 4; ++r) {
                int node = g * 16 + kg * 4 + r;
                float v = fmaxf(acc[t][r] + bv[t], 0.0f);
                if (OUT_BF16)
                    ((unsigned short*)outp)[(size_t)node * FEAT + t * 16 + col] = f2bf(v);
                else
                    ((float*)outp)[(size_t)node * FEAT + t * 16 + col] = v;
            }
        }
    }
}

extern "C" void kernel_launch(void* const* d_in, const int* in_sizes, int n_in,
                              void* d_out, int out_size, void* d_ws, size_t ws_size,
                              hipStream_t stream) {
    const float* x   = (const float*)d_in[0];
    const int* ei    = (const int*)d_in[1];
    const float* Wl1 = (const float*)d_in[2];
    const float* b1  = (const float*)d_in[3];
    const float* Wr1 = (const float*)d_in[4];
    const float* Wl2 = (const float*)d_in[5];
    const float* b2  = (const float*)d_in[6];
    const float* Wr2 = (const float*)d_in[7];

    const int E = in_sizes[1] / 2;  // 1,600,000
    const int* src = ei;
    const int* dst = ei + E;
    const int N = N_NODES;

    const int n2 = NBINS * NTILES;               // 400384
    const int TE = (E + NTILES - 1) / NTILES;    // 1563
    const int NB2 = (n2 + SCAN_B - 1) / SCAN_B;  // 391 (<=512 for scan2)

    // workspace layout (int-counts %4==0 -> every bf16 buffer 16B-aligned)
    int* H      = (int*)d_ws;                            // n2
    int* P      = H + n2;                                // n2+8
    int* bsum   = P + (n2 + 8);                          // 512
    unsigned int* packed = (unsigned int*)(bsum + 512);  // E
    int* rowptr = (int*)(packed + E);                    // N+8
    int* ssrc   = rowptr + (N + 8);                      // E
    unsigned short* meanb = (unsigned short*)(ssrc + E); // N*64 bf16
    unsigned short* xb    = meanb + (size_t)N * FEAT;    // N*64 bf16
    unsigned short* hb    = xb + (size_t)N * FEAT;       // N*64 bf16
    float* out  = (float*)d_out;

    const int NG = N / 16;  // 6250 MFMA node-groups

    // ---- feature conversion + partition/sort (reused by both layers) ----
    cvt_bf16_kernel<<<(N * FEAT / 8 + 255) / 256, 256, 0, stream>>>(x, xb, N * FEAT / 8);
    tile_hist_kernel<<<NTILES, 256, 0, stream>>>(dst, H, E, TE);
    scan1_kernel<<<NB2, SCAN_B, 0, stream>>>(H, P, bsum, n2);
    scan2_kernel<<<1, 512, 0, stream>>>(bsum, NB2);
    scan3_kernel<<<(n2 + 256) / 256, 256, 0, stream>>>(P, bsum, n2, E);
    scatter_bucket_kernel<<<NTILES, 256, 0, stream>>>(src, dst, P, packed, E, TE);
    bucket_sort_kernel<<<NBINS, 256, 0, stream>>>(packed, P, rowptr, ssrc, E);

    // ---- layer 1 ----
    agg_bf16_kernel<<<(N * 8 + 255) / 256, 256, 0, stream>>>(xb, rowptr, ssrc, meanb, N);
    mfma_linear_kernel<true><<<256, 256, 0, stream>>>(meanb, xb, Wl1, b1, Wr1, hb, NG);

    // ---- layer 2 ----
    agg_bf16_kernel<<<(N * 8 + 255) / 256, 256, 0, stream>>>(hb, rowptr, ssrc, meanb, N);
    mfma_linear_kernel<false><<<256, 256, 0, stream>>>(meanb, hb, Wl2, b2, Wr2, out, NG);
}

// Round 14
// 176.880 us; speedup vs baseline: 1.2710x; 1.0322x over previous
//
#include <hip/hip_runtime.h>
#include <stdint.h>

#define N_NODES 100000
#define FEAT 64
#define SCAN_B 1024
#define BKT 256                                  // dst nodes per bucket
#define NBINS ((N_NODES + BKT - 1) / BKT)        // 391
#define NTILES 1024                              // edge tiles (4 wg/CU)
#define NRANGE 4                                 // src ranges (25000 nodes = 3.2MB, fits XCD L2)
#define RANGE_DIV 25000
#define SRC_MASK 0x00FFFFFFu

typedef __attribute__((ext_vector_type(8))) short bf16x8;
typedef __attribute__((ext_vector_type(4))) float f32x4;

__device__ __forceinline__ unsigned short f2bf(float f) {
    unsigned int u = __float_as_uint(f);
    u += 0x7fffu + ((u >> 16) & 1u);  // RNE
    return (unsigned short)(u >> 16);
}
__device__ __forceinline__ float bflo(unsigned int u) { return __uint_as_float(u << 16); }
__device__ __forceinline__ float bfhi(unsigned int u) { return __uint_as_float(u & 0xffff0000u); }

// ---- one-time fp32 -> bf16 feature conversion ----
__global__ __launch_bounds__(256) void cvt_bf16_kernel(
    const float* __restrict__ in, unsigned short* __restrict__ out, int n8) {
    int i = blockIdx.x * blockDim.x + threadIdx.x;
    if (i >= n8) return;
    float4 a = ((const float4*)in)[i * 2];
    float4 b = ((const float4*)in)[i * 2 + 1];
    uint4 r;
    r.x = (unsigned int)f2bf(a.x) | ((unsigned int)f2bf(a.y) << 16);
    r.y = (unsigned int)f2bf(a.z) | ((unsigned int)f2bf(a.w) << 16);
    r.z = (unsigned int)f2bf(b.x) | ((unsigned int)f2bf(b.y) << 16);
    r.w = (unsigned int)f2bf(b.z) | ((unsigned int)f2bf(b.w) << 16);
    ((uint4*)out)[i] = r;
}

// ---- bucket partition build ----

__global__ __launch_bounds__(256) void tile_hist_kernel(
    const int* __restrict__ dst, int* __restrict__ H, int nE, int tileEdges) {
    __shared__ int hist[NBINS];
    const int tile = blockIdx.x;
    const int tid = threadIdx.x;
    for (int i = tid; i < NBINS; i += 256) hist[i] = 0;
    __syncthreads();
    int e0 = tile * tileEdges;
    int e1 = min(e0 + tileEdges, nE);
    for (int e = e0 + tid; e < e1; e += 256) atomicAdd(&hist[dst[e] >> 8], 1);
    __syncthreads();
    for (int i = tid; i < NBINS; i += 256) H[i * NTILES + tile] = hist[i];
}

__global__ __launch_bounds__(SCAN_B) void scan1_kernel(
    const int* __restrict__ deg, int* __restrict__ P,
    int* __restrict__ bsum, int n) {
    __shared__ int tmp[SCAN_B];
    int t = threadIdx.x;
    int gid = blockIdx.x * SCAN_B + t;
    int v = (gid < n) ? deg[gid] : 0;
    tmp[t] = v;
    __syncthreads();
    for (int off = 1; off < SCAN_B; off <<= 1) {
        int a = (t >= off) ? tmp[t - off] : 0;
        __syncthreads();
        tmp[t] += a;
        __syncthreads();
    }
    if (gid < n) P[gid] = tmp[t] - v;  // exclusive
    if (t == SCAN_B - 1) bsum[blockIdx.x] = tmp[t];
}

__global__ __launch_bounds__(512) void scan2_kernel(int* __restrict__ bsum, int nb) {
    __shared__ int tmp[512];
    int t = threadIdx.x;
    int v = (t < nb) ? bsum[t] : 0;
    tmp[t] = v;
    __syncthreads();
    for (int off = 1; off < 512; off <<= 1) {
        int a = (t >= off) ? tmp[t - off] : 0;
        __syncthreads();
        tmp[t] += a;
        __syncthreads();
    }
    if (t < nb) bsum[t] = tmp[t] - v;  // exclusive
}

__global__ __launch_bounds__(256) void scan3_kernel(
    int* __restrict__ P, const int* __restrict__ bsum, int n, int total) {
    int gid = blockIdx.x * blockDim.x + threadIdx.x;
    if (gid < n) P[gid] += bsum[gid >> 10];
    if (gid == 0) P[n] = total;
}

__global__ __launch_bounds__(256) void scatter_bucket_kernel(
    const int* __restrict__ src, const int* __restrict__ dst,
    const int* __restrict__ P, unsigned int* __restrict__ packed,
    int nE, int tileEdges) {
    __shared__ int cur[NBINS];
    const int tile = blockIdx.x;
    const int tid = threadIdx.x;
    for (int i = tid; i < NBINS; i += 256) cur[i] = P[i * NTILES + tile];
    __syncthreads();
    int e0 = tile * tileEdges;
    int e1 = min(e0 + tileEdges, nE);
    for (int e = e0 + tid; e < e1; e += 256) {
        int d = dst[e];
        int pos = atomicAdd(&cur[d >> 8], 1);
        packed[pos] = ((unsigned int)(d & (BKT - 1)) << 24) | (unsigned int)src[e];
    }
}

// 1024-bin counting sort per bucket: key = dloc*4 + src/25000.
// Produces ssrc sorted by (dst, src-range), rowptr2[node*4+c], invdeg[node].
// Thread t owns node dloc=t's 4 range-counts -> invdeg for free.
__global__ __launch_bounds__(256) void bucket_sort_kernel(
    const unsigned int* __restrict__ packed,
    const int* __restrict__ P,
    int* __restrict__ rowptr2,
    float* __restrict__ invdeg,
    int* __restrict__ ssrc,
    int nE) {
    __shared__ int hist[BKT * NRANGE];
    __shared__ int cur[BKT * NRANGE];
    __shared__ int scanbuf[BKT];
    const int b = blockIdx.x;
    const int t = threadIdx.x;

#pragma unroll
    for (int i = 0; i < NRANGE; ++i) hist[t * NRANGE + i] = 0;
    __syncthreads();
    const int start = P[b * NTILES];
    const int end = (b + 1 < NBINS) ? P[(b + 1) * NTILES] : nE;
    for (int j = start + t; j < end; j += 256) {
        unsigned int p = packed[j];
        int s = (int)(p & SRC_MASK);
        atomicAdd(&hist[(int)(p >> 24) * NRANGE + s / RANGE_DIV], 1);
    }
    __syncthreads();

    int c0 = hist[t * NRANGE + 0], c1 = hist[t * NRANGE + 1];
    int c2 = hist[t * NRANGE + 2], c3 = hist[t * NRANGE + 3];
    int tot = c0 + c1 + c2 + c3;
    int node = b * BKT + t;
    if (node < N_NODES) invdeg[node] = 1.0f / (float)(tot > 0 ? tot : 1);
    scanbuf[t] = tot;
    __syncthreads();
    for (int off = 1; off < 256; off <<= 1) {
        int a = (t >= off) ? scanbuf[t - off] : 0;
        __syncthreads();
        scanbuf[t] += a;
        __syncthreads();
    }
    int base = start + scanbuf[t] - tot;  // exclusive within bucket
    int e0 = base, e1 = base + c0, e2 = e1 + c1, e3 = e2 + c2;
    // phantom nodes (>=N, last bucket) get base==end: gives rowptr2[N*4]=E. ✓
    rowptr2[node * 4 + 0] = e0;
    rowptr2[node * 4 + 1] = e1;
    rowptr2[node * 4 + 2] = e2;
    rowptr2[node * 4 + 3] = e3;
    cur[t * NRANGE + 0] = e0;
    cur[t * NRANGE + 1] = e1;
    cur[t * NRANGE + 2] = e2;
    cur[t * NRANGE + 3] = e3;
    __syncthreads();

    for (int j = start + t; j < end; j += 256) {
        unsigned int p = packed[j];
        int s = (int)(p & SRC_MASK);
        int pos = atomicAdd(&cur[(int)(p >> 24) * NRANGE + s / RANGE_DIV], 1);
        ssrc[pos] = s;
    }
}

// Range-partitioned partial aggregation. Block (bin = blockIdx>>2,
// c = blockIdx&3): gathers ONLY srcs in [c*25000,(c+1)*25000) = 3.2MB.
// XCD = blockIdx%8 round-robin => range c pinned to XCDs {c, c+4} -> table
// range is L2-resident. Keeps R11's 8-lane 128B row-gather shape.
// Writes bf16 partial sums (no mean division) to part[c][N][64].
__global__ __launch_bounds__(256) void agg_part_kernel(
    const unsigned short* __restrict__ featb,   // [N][64] bf16
    const int* __restrict__ rowptr2,            // [N*4+4]
    const int* __restrict__ ssrc,
    unsigned short* __restrict__ part,          // [4][N][64] bf16
    int nNodes) {
    const int c = blockIdx.x & 3;
    const int bin = blockIdx.x >> 2;
    const int slot = threadIdx.x >> 3;  // 0..31
    const int chunk = threadIdx.x & 7;
    const uint4* feat16 = (const uint4*)featb;

#pragma unroll
    for (int g = 0; g < 8; ++g) {
        int node = bin * BKT + g * 32 + slot;
        if (node >= nNodes) continue;
        int beg = rowptr2[node * 4 + c];
        int end = rowptr2[node * 4 + c + 1];
        float acc0 = 0.f, acc1 = 0.f, acc2 = 0.f, acc3 = 0.f;
        float acc4 = 0.f, acc5 = 0.f, acc6 = 0.f, acc7 = 0.f;

#define ADDROW(a)                                 \
    acc0 += bflo((a).x); acc1 += bfhi((a).x);     \
    acc2 += bflo((a).y); acc3 += bfhi((a).y);     \
    acc4 += bflo((a).z); acc5 += bfhi((a).z);     \
    acc6 += bflo((a).w); acc7 += bfhi((a).w);

        int j = beg;
        for (; j + 4 <= end; j += 4) {
            int s0 = ssrc[j + 0];
            int s1 = ssrc[j + 1];
            int s2 = ssrc[j + 2];
            int s3 = ssrc[j + 3];
            uint4 a0 = feat16[(size_t)s0 * 8 + chunk];
            uint4 a1 = feat16[(size_t)s1 * 8 + chunk];
            uint4 a2 = feat16[(size_t)s2 * 8 + chunk];
            uint4 a3 = feat16[(size_t)s3 * 8 + chunk];
            ADDROW(a0) ADDROW(a1) ADDROW(a2) ADDROW(a3)
        }
        for (; j < end; ++j) {
            uint4 a = feat16[(size_t)ssrc[j] * 8 + chunk];
            ADDROW(a)
        }
#undef ADDROW

        uint4 r;
        r.x = (unsigned int)f2bf(acc0) | ((unsigned int)f2bf(acc1) << 16);
        r.y = (unsigned int)f2bf(acc2) | ((unsigned int)f2bf(acc3) << 16);
        r.z = (unsigned int)f2bf(acc4) | ((unsigned int)f2bf(acc5) << 16);
        r.w = (unsigned int)f2bf(acc6) | ((unsigned int)f2bf(acc7) << 16);
        ((uint4*)part)[((size_t)c * N_NODES + node) * 8 + chunk] = r;
    }
}

// ---- MFMA linear with fused partial-reduce:
// out = relu(((sum_c part_c) * invdeg) @ Wl^T + x @ Wr^T + b) ----

__device__ __forceinline__ bf16x8 pack8(const float* __restrict__ p) {
    float4 a = *(const float4*)p;
    float4 b = *(const float4*)(p + 4);
    bf16x8 r;
    r[0] = (short)f2bf(a.x); r[1] = (short)f2bf(a.y);
    r[2] = (short)f2bf(a.z); r[3] = (short)f2bf(a.w);
    r[4] = (short)f2bf(b.x); r[5] = (short)f2bf(b.y);
    r[6] = (short)f2bf(b.z); r[7] = (short)f2bf(b.w);
    return r;
}

template <bool OUT_BF16>
__global__ __launch_bounds__(256) void mfma_linear_kernel(
    const unsigned short* __restrict__ part,   // [4][N][64] bf16 partials
    const float* __restrict__ invdeg,          // [N]
    const unsigned short* __restrict__ xb,     // [N][64] bf16
    const float* __restrict__ Wl,
    const float* __restrict__ bias,
    const float* __restrict__ Wr,
    void* __restrict__ outp,
    int nGroups) {
    const int lane = (int)(threadIdx.x & 63);
    const int col = lane & 15;
    const int kg = lane >> 4;
    const uint4* part4 = (const uint4*)part;

    bf16x8 bfr[4][4];
#pragma unroll
    for (int t = 0; t < 4; ++t) {
        const int n = t * 16 + col;
#pragma unroll
        for (int kk = 0; kk < 4; ++kk) {
            const float* w = (kk < 2 ? Wl : Wr) + n * 64 + (kk & 1) * 32 + kg * 8;
            bfr[t][kk] = pack8(w);
        }
    }
    float bv[4];
#pragma unroll
    for (int t = 0; t < 4; ++t) bv[t] = bias[t * 16 + col];

    const int wave = (int)((blockIdx.x * blockDim.x + threadIdx.x) >> 6);
    const int nWaves = (int)((gridDim.x * blockDim.x) >> 6);

    for (int g = wave; g < nGroups; g += nWaves) {
        const int arow = g * 16 + col;
        const float invd = invdeg[arow];
        const unsigned short* xrow = xb + (size_t)arow * FEAT + kg * 8;

        f32x4 acc[4];
#pragma unroll
        for (int t = 0; t < 4; ++t) acc[t] = (f32x4){0.f, 0.f, 0.f, 0.f};

#pragma unroll
        for (int kk = 0; kk < 4; ++kk) {
            bf16x8 a;
            if (kk < 2) {
                // fused reduce: mean chunk = (sum of 4 partials) * invdeg
                const size_t u = (size_t)arow * 8 + (kk & 1) * 4 + kg;
                uint4 q0 = part4[u];
                uint4 q1 = part4[(size_t)1 * N_NODES * 8 + u];
                uint4 q2 = part4[(size_t)2 * N_NODES * 8 + u];
                uint4 q3 = part4[(size_t)3 * N_NODES * 8 + u];
                float m0 = (bflo(q0.x) + bflo(q1.x)) + (bflo(q2.x) + bflo(q3.x));
                float m1 = (bfhi(q0.x) + bfhi(q1.x)) + (bfhi(q2.x) + bfhi(q3.x));
                float m2 = (bflo(q0.y) + bflo(q1.y)) + (bflo(q2.y) + bflo(q3.y));
                float m3 = (bfhi(q0.y) + bfhi(q1.y)) + (bfhi(q2.y) + bfhi(q3.y));
                float m4 = (bflo(q0.z) + bflo(q1.z)) + (bflo(q2.z) + bflo(q3.z));
                float m5 = (bfhi(q0.z) + bfhi(q1.z)) + (bfhi(q2.z) + bfhi(q3.z));
                float m6 = (bflo(q0.w) + bflo(q1.w)) + (bflo(q2.w) + bflo(q3.w));
                float m7 = (bfhi(q0.w) + bfhi(q1.w)) + (bfhi(q2.w) + bfhi(q3.w));
                a[0] = (short)f2bf(m0 * invd); a[1] = (short)f2bf(m1 * invd);
                a[2] = (short)f2bf(m2 * invd); a[3] = (short)f2bf(m3 * invd);
                a[4] = (short)f2bf(m4 * invd); a[5] = (short)f2bf(m5 * invd);
                a[6] = (short)f2bf(m6 * invd); a[7] = (short)f2bf(m7 * invd);
            } else {
                a = *(const bf16x8*)(xrow + (kk & 1) * 32);
            }
#pragma unroll
            for (int t = 0; t < 4; ++t)
                acc[t] = __builtin_amdgcn_mfma_f32_16x16x32_bf16(a, bfr[t][kk], acc[t], 0, 0, 0);
        }

#pragma unroll
        for (int t = 0; t < 4; ++t) {
#pragma unroll
            for (int r = 0; r < 4; ++r) {
                int node = g * 16 + kg * 4 + r;
                float v = fmaxf(acc[t][r] + bv[t], 0.0f);
                if (OUT_BF16)
                    ((unsigned short*)outp)[(size_t)node * FEAT + t * 16 + col] = f2bf(v);
                else
                    ((float*)outp)[(size_t)node * FEAT + t * 16 + col] = v;
            }
        }
    }
}

extern "C" void kernel_launch(void* const* d_in, const int* in_sizes, int n_in,
                              void* d_out, int out_size, void* d_ws, size_t ws_size,
                              hipStream_t stream) {
    const float* x   = (const float*)d_in[0];
    const int* ei    = (const int*)d_in[1];
    const float* Wl1 = (const float*)d_in[2];
    const float* b1  = (const float*)d_in[3];
    const float* Wr1 = (const float*)d_in[4];
    const float* Wl2 = (const float*)d_in[5];
    const float* b2  = (const float*)d_in[6];
    const float* Wr2 = (const float*)d_in[7];

    const int E = in_sizes[1] / 2;  // 1,600,000
    const int* src = ei;
    const int* dst = ei + E;
    const int N = N_NODES;

    const int n2 = NBINS * NTILES;               // 400384
    const int TE = (E + NTILES - 1) / NTILES;    // 1563
    const int NB2 = (n2 + SCAN_B - 1) / SCAN_B;  // 391

    // workspace layout (element counts %4==0 -> 16B alignment throughout)
    int* H        = (int*)d_ws;                          // n2
    int* P        = H + n2;                              // n2+8
    int* bsum     = P + (n2 + 8);                        // 512
    int* rowptr2  = bsum + 512;                          // NBINS*1024 = 400384 (covers N*4+tail)
    float* invdeg = (float*)(rowptr2 + n2);              // N
    int* ssrc     = (int*)(invdeg + N);                  // E
    unsigned short* xb = (unsigned short*)(ssrc + E);    // N*64 bf16
    unsigned short* hb = xb + (size_t)N * FEAT;          // N*64 bf16
    unsigned short* part = hb + (size_t)N * FEAT;        // 4*N*64 bf16 (51.2MB)
    unsigned int* packed = (unsigned int*)part;          // E (dead before part is written)
    float* out = (float*)d_out;

    const int NG = N / 16;  // 6250 MFMA node-groups

    // ---- feature conversion + partition/sort (reused by both layers) ----
    cvt_bf16_kernel<<<(N * FEAT / 8 + 255) / 256, 256, 0, stream>>>(x, xb, N * FEAT / 8);
    tile_hist_kernel<<<NTILES, 256, 0, stream>>>(dst, H, E, TE);
    scan1_kernel<<<NB2, SCAN_B, 0, stream>>>(H, P, bsum, n2);
    scan2_kernel<<<1, 512, 0, stream>>>(bsum, NB2);
    scan3_kernel<<<(n2 + 256) / 256, 256, 0, stream>>>(P, bsum, n2, E);
    scatter_bucket_kernel<<<NTILES, 256, 0, stream>>>(src, dst, P, packed, E, TE);
    bucket_sort_kernel<<<NBINS, 256, 0, stream>>>(packed, P, rowptr2, invdeg, ssrc, E);

    // ---- layer 1 ----
    agg_part_kernel<<<NBINS * NRANGE, 256, 0, stream>>>(xb, rowptr2, ssrc, part, N);
    mfma_linear_kernel<true><<<256, 256, 0, stream>>>(part, invdeg, xb, Wl1, b1, Wr1, hb, NG);

    // ---- layer 2 ----
    agg_part_kernel<<<NBINS * NRANGE, 256, 0, stream>>>(hb, rowptr2, ssrc, part, N);
    mfma_linear_kernel<false><<<256, 256, 0, stream>>>(part, invdeg, hb, Wl2, b2, Wr2, out, NG);
}